// Round 10
// baseline (134.161 us; speedup 1.0000x reference)
//
#include <hip/hip_runtime.h>
#include <stdint.h>

typedef __attribute__((ext_vector_type(8))) short bf16x8;
typedef __attribute__((ext_vector_type(4))) float f32x4;
typedef __attribute__((ext_vector_type(4))) float float4v;
typedef __attribute__((ext_vector_type(8))) unsigned short u16x8;

#define DEV __device__ __forceinline__

DEV unsigned short f2bf(float f) {
    union { float f; uint32_t u; } v; v.f = f;
    uint32_t u = v.u;
    return (unsigned short)((u + 0x7FFFu + ((u >> 16) & 1u)) >> 16);
}

DEV unsigned int cvt_pk_bf16(float lo, float hi) {
    unsigned int r;
    asm("v_cvt_pk_bf16_f32 %0, %1, %2" : "=v"(r) : "v"(lo), "v"(hi));
    return r;
}

#if __has_builtin(__builtin_amdgcn_global_load_lds)
#define HAVE_GLDS 1
typedef const unsigned char __attribute__((address_space(1)))* as1p;
typedef unsigned char __attribute__((address_space(3)))* as3p;
DEV void gload16(const unsigned short* g, unsigned short* l) {
    __builtin_amdgcn_global_load_lds((as1p)(const void*)g, (as3p)(void*)l, 16, 0, 0);
}
#else
#define HAVE_GLDS 0
#endif

// ---------------------------------------------------------------------------
// 1) fp32 -> bf16 convert (x)
// ---------------------------------------------------------------------------
__global__ void k_cvt_x(const float* __restrict__ x, unsigned short* __restrict__ xb, int n4) {
    int i = blockIdx.x * blockDim.x + threadIdx.x;
    if (i >= n4) return;
    float4v v = *(const float4v*)(x + (size_t)i * 4);
    union { unsigned short s[4]; uint64_t q; } o;
    o.s[0] = f2bf(v[0]); o.s[1] = f2bf(v[1]); o.s[2] = f2bf(v[2]); o.s[3] = f2bf(v[3]);
    *(uint64_t*)(xb + (size_t)i * 4) = o.q;
}

// ---------------------------------------------------------------------------
// 2) fp32 [R][C] -> bf16 [C][R] convert + transpose
// ---------------------------------------------------------------------------
__global__ void k_cvt_tr_w(const float* __restrict__ w, unsigned short* __restrict__ wt,
                           int R, int C) {
    __shared__ alignas(16) unsigned short tile[64][65];
    const int t = threadIdx.x;
    const int tr = blockIdx.y * 64, tc = blockIdx.x * 64;
#pragma unroll
    for (int p = 0; p < 4; ++p) {
        int r = p * 16 + (t >> 4);
        int c = (t & 15) * 4;
        float4v v = *(const float4v*)(w + (size_t)(tr + r) * C + tc + c);
#pragma unroll
        for (int j = 0; j < 4; ++j) tile[r][c + j] = f2bf(v[j]);
    }
    __syncthreads();
#pragma unroll
    for (int p = 0; p < 2; ++p) {
        int r2 = p * 32 + (t >> 3);
        int k0 = (t & 7) * 8;
        u16x8 o;
#pragma unroll
        for (int j = 0; j < 8; ++j) o[j] = tile[k0 + j][r2];
        *(u16x8*)(wt + (size_t)(tc + r2) * R + tr + k0) = o;
    }
}

// ---------------------------------------------------------------------------
// 3) bf16 GEMM (unchanged from R9): 128M x BN tile, BK=64, 4 waves, GLDS
//    staging, fused V-transpose epilogue for the QKV GEMM.
// ---------------------------------------------------------------------------
template <int OUT_BF16, int BN>
__global__ __launch_bounds__(256)
void k_gemm_bt(const unsigned short* __restrict__ A,
               const unsigned short* __restrict__ Bt,
               void* __restrict__ Cp, const float* __restrict__ bias,
               unsigned short* __restrict__ vt_out,
               int M, int N, int K) {
    constexpr int NFR = BN / 32;
    __shared__ alignas(16) unsigned short lA[128 * 64];
    __shared__ alignas(16) unsigned short lB[BN * 64];
    const int t = threadIdx.x;
    const int w = t >> 6, l = t & 63;
    const int l15 = l & 15, l4 = l >> 4;
    const int wm = (w >> 1) * 64, wn = (w & 1) * (BN / 2);
    const size_t bm = (size_t)blockIdx.y * 128, bn = (size_t)blockIdx.x * BN;

    int offA[4][2], offB[NFR][2];
#pragma unroll
    for (int f = 0; f < 4; ++f) {
        const int ra = wm + f * 16 + l15;
#pragma unroll
        for (int kc = 0; kc < 2; ++kc)
            offA[f][kc] = ra * 64 + (((kc * 4 + l4) ^ (ra & 7)) << 3);
    }
#pragma unroll
    for (int f = 0; f < NFR; ++f) {
        const int rb = wn + f * 16 + l15;
#pragma unroll
        for (int kc = 0; kc < 2; ++kc)
            offB[f][kc] = rb * 64 + (((kc * 4 + l4) ^ (rb & 7)) << 3);
    }

#if HAVE_GLDS
    const int srow8 = l >> 3;
    const int scol  = (l & 7) ^ srow8;
    const unsigned short* gA = A  + (bm + w * 32 + srow8) * (size_t)K + scol * 8;
    const unsigned short* gB = Bt + (bn + w * (BN / 4) + srow8) * (size_t)K + scol * 8;
    unsigned short* dA = lA + (w * 32) * 64;
    unsigned short* dB = lB + (w * (BN / 4)) * 64;
#else
    const int srow = t >> 3, sslot = t & 7;
    const int swoff = srow * 64 + ((sslot ^ (srow & 7)) << 3);
    const unsigned short* pA = A + (bm + srow) * (size_t)K + sslot * 8;
    const unsigned short* pB = Bt + (bn + srow) * (size_t)K + sslot * 8;
#endif

    const f32x4 zf = {0.f, 0.f, 0.f, 0.f};
    f32x4 acc[4][NFR];
#pragma unroll
    for (int i = 0; i < 4; ++i)
#pragma unroll
        for (int j = 0; j < NFR; ++j) acc[i][j] = zf;

    for (int kt = 0; kt < K; kt += 64) {
#if HAVE_GLDS
        __syncthreads();
#pragma unroll
        for (int i = 0; i < 4; ++i)
            gload16(gA + (size_t)i * 8 * K + kt, dA + i * 8 * 64);
#pragma unroll
        for (int i = 0; i < BN / 32; ++i)
            gload16(gB + (size_t)i * 8 * K + kt, dB + i * 8 * 64);
        __syncthreads();
#else
        bf16x8 ra[4], rb[BN / 32];
#pragma unroll
        for (int p = 0; p < 4; ++p)
            ra[p] = *(const bf16x8*)(pA + (size_t)p * 32 * K + kt);
#pragma unroll
        for (int p = 0; p < BN / 32; ++p)
            rb[p] = *(const bf16x8*)(pB + (size_t)p * 32 * K + kt);
        __syncthreads();
#pragma unroll
        for (int p = 0; p < 4; ++p)
            *(bf16x8*)(lA + p * 32 * 64 + swoff) = ra[p];
#pragma unroll
        for (int p = 0; p < BN / 32; ++p)
            *(bf16x8*)(lB + p * 32 * 64 + swoff) = rb[p];
        __syncthreads();
#endif
#pragma unroll
        for (int kc = 0; kc < 2; ++kc) {
            bf16x8 af[4], bfr[NFR];
#pragma unroll
            for (int f = 0; f < 4; ++f) af[f] = *(const bf16x8*)(lA + offA[f][kc]);
#pragma unroll
            for (int f = 0; f < NFR; ++f) bfr[f] = *(const bf16x8*)(lB + offB[f][kc]);
#pragma unroll
            for (int mf = 0; mf < 4; ++mf)
#pragma unroll
                for (int nf = 0; nf < NFR; ++nf)
                    acc[mf][nf] = __builtin_amdgcn_mfma_f32_16x16x32_bf16(
                        af[mf], bfr[nf], acc[mf][nf], 0, 0, 0);
        }
    }

    if (OUT_BF16) {
        if (vt_out && bn >= 2048) {
            const int bb = (int)(bm >> 11);
            const int n0 = (int)(bm & 2047) + wm + l4 * 4;
#pragma unroll
            for (int nf = 0; nf < NFR; ++nf) {
                const int d = (int)(bn - 2048) + wn + nf * 16 + l15;
                unsigned short* vrow = vt_out + ((size_t)(bb * 16 + (d >> 6)) * 64 + (d & 63)) * 2048;
#pragma unroll
                for (int mf = 0; mf < 4; ++mf) {
                    union { unsigned short s[4]; uint64_t q; } u;
#pragma unroll
                    for (int j = 0; j < 4; ++j) u.s[j] = f2bf(acc[mf][nf][j]);
                    *(uint64_t*)(vrow + n0 + mf * 16) = u.q;
                }
            }
        } else {
            unsigned short* C = (unsigned short*)Cp;
#pragma unroll
            for (int mf = 0; mf < 4; ++mf)
#pragma unroll
                for (int nf = 0; nf < NFR; ++nf) {
                    const size_t row = bm + wm + mf * 16 + l4 * 4;
                    const size_t col = bn + wn + nf * 16 + l15;
#pragma unroll
                    for (int j = 0; j < 4; ++j)
                        C[(row + j) * (size_t)N + col] = f2bf(acc[mf][nf][j]);
                }
        }
    } else {
        float* C = (float*)Cp;
#pragma unroll
        for (int nf = 0; nf < NFR; ++nf) {
            const size_t col = bn + wn + nf * 16 + l15;
            const float bv = bias[col];
#pragma unroll
            for (int mf = 0; mf < 4; ++mf) {
                const size_t row = bm + wm + mf * 16 + l4 * 4;
#pragma unroll
                for (int j = 0; j < 4; ++j)
                    C[(row + j) * (size_t)N + col] = acc[mf][nf][j] + bv;
            }
        }
    }
}

// ---------------------------------------------------------------------------
// 5) Flash attention, swapped-QK, verified 16x16x32 paths only.
//    R10 delta vs R9: each wave owns 32 q rows (2 x 16-q sub-blocks through
//    the identical verified paths). K A-frags and V B-frags are read from
//    LDS ONCE per iter and reused by both sub-blocks -> per-q LDS read
//    traffic drops ~1.8x (the measured bottleneck). Block = 128 q, grid
//    512 = 2 blocks/CU, launch_bounds(256,2) for the 256-VGPR budget.
// ---------------------------------------------------------------------------
__global__ __launch_bounds__(256, 2)
void k_attn(const unsigned short* __restrict__ qkv, const unsigned short* __restrict__ vt,
            unsigned short* __restrict__ attn_out) {
    __shared__ alignas(16) unsigned short lK[2][64 * 64];
    __shared__ alignas(16) unsigned short lV[2][64 * 64];
    __shared__ alignas(16) unsigned short lP[4][2][16 * 64];
    const int t = threadIdx.x, w = t >> 6, l = t & 63;
    const int l15 = l & 15, l4 = l >> 4;
    const int bh = blockIdx.y, b = bh >> 4, h = bh & 15;
    const int qb = blockIdx.x * 128;
    const float QSCALE = 0.18033688011112042f;   // 0.125 * log2(e)

    // Q B-frags for the wave's two 16-q sub-blocks
    bf16x8 aq[2][2];
#pragma unroll
    for (int qs = 0; qs < 2; ++qs) {
        const unsigned short* qptr =
            qkv + (size_t)(b * 2048 + qb + w * 32 + qs * 16 + l15) * 3072 + h * 64 + l4 * 8;
        aq[qs][0] = *(const bf16x8*)(qptr);
        aq[qs][1] = *(const bf16x8*)(qptr + 32);
    }

    const int srow = t >> 3, sslot = t & 7;
    const int swoff = srow * 64 + ((sslot ^ (srow & 7)) << 3);
    const unsigned short* kptr = qkv + (size_t)(b * 2048 + srow) * 3072 + 1024 + h * 64 + sslot * 8;
    const unsigned short* vptr = vt + (size_t)(bh * 64 + srow) * 2048 + sslot * 8;

    int offK[4][2];
#pragma unroll
    for (int nf = 0; nf < 4; ++nf) {
        const int r = nf * 16 + l15;
#pragma unroll
        for (int kc = 0; kc < 2; ++kc)
            offK[nf][kc] = r * 64 + (((kc * 4 + l4) ^ (r & 7)) << 3);
    }
    int offPw[4];
#pragma unroll
    for (int nf = 0; nf < 4; ++nf) {
        const int c = nf * 16 + l4 * 4;
        offPw[nf] = l15 * 64 + (((c >> 3) ^ (l15 & 7)) << 3) + (c & 7);
    }

    const f32x4 zf = {0.f, 0.f, 0.f, 0.f};
    f32x4 o[2][4];
#pragma unroll
    for (int qs = 0; qs < 2; ++qs)
#pragma unroll
        for (int df = 0; df < 4; ++df) o[qs][df] = zf;
    f32x4 accl[2] = {zf, zf};
    float m_run[2] = {-1e30f, -1e30f};
    const bf16x8 ones8 = {(short)0x3F80, (short)0x3F80, (short)0x3F80, (short)0x3F80,
                          (short)0x3F80, (short)0x3F80, (short)0x3F80, (short)0x3F80};

    // prologue: stage tile 0 into buffer 0
    {
        bf16x8 rk[2], rv[2];
#pragma unroll
        for (int p = 0; p < 2; ++p) {
            rk[p] = *(const bf16x8*)(kptr + (size_t)(p * 32) * 3072);
            rv[p] = *(const bf16x8*)(vptr + (size_t)(p * 32) * 2048);
        }
#pragma unroll
        for (int p = 0; p < 2; ++p) {
            *(bf16x8*)(&lK[0][0] + p * 32 * 64 + swoff) = rk[p];
            *(bf16x8*)(&lV[0][0] + p * 32 * 64 + swoff) = rv[p];
        }
        __syncthreads();
    }

    for (int kt = 0; kt < 2048; kt += 64) {
        const int cur = (kt >> 6) & 1;
        const unsigned short* K = &lK[cur][0];
        const unsigned short* V = &lV[cur][0];

        bf16x8 rk[2], rv[2];
        const bool more = (kt + 64) < 2048;
        if (more) {
#pragma unroll
            for (int p = 0; p < 2; ++p) {
                rk[p] = *(const bf16x8*)(kptr + (size_t)(kt + 64 + p * 32) * 3072);
                rv[p] = *(const bf16x8*)(vptr + (size_t)(p * 32) * 2048 + kt + 64);
            }
        }

        // K A-frags read ONCE, reused by both q sub-blocks
        bf16x8 kf[4][2];
#pragma unroll
        for (int nf = 0; nf < 4; ++nf) {
            kf[nf][0] = *(const bf16x8*)(K + offK[nf][0]);
            kf[nf][1] = *(const bf16x8*)(K + offK[nf][1]);
        }

        // S^T = K Q^T for both sub-blocks
        f32x4 s[2][4];
        __builtin_amdgcn_s_setprio(1);
#pragma unroll
        for (int qs = 0; qs < 2; ++qs)
#pragma unroll
            for (int nf = 0; nf < 4; ++nf) {
                f32x4 a = zf;
                a = __builtin_amdgcn_mfma_f32_16x16x32_bf16(kf[nf][0], aq[qs][0], a, 0, 0, 0);
                a = __builtin_amdgcn_mfma_f32_16x16x32_bf16(kf[nf][1], aq[qs][1], a, 0, 0, 0);
                s[qs][nf] = a;
            }
        __builtin_amdgcn_s_setprio(0);

        // per-sub-block row max + defer-max bookkeeping
        float mx[2];
#pragma unroll
        for (int qs = 0; qs < 2; ++qs) {
            float m = fmaxf(fmaxf(s[qs][0][0], s[qs][0][1]), s[qs][0][2]);
            m = fmaxf(fmaxf(m, s[qs][0][3]), s[qs][1][0]);
            m = fmaxf(fmaxf(m, s[qs][1][1]), s[qs][1][2]);
            m = fmaxf(fmaxf(m, s[qs][1][3]), s[qs][2][0]);
            m = fmaxf(fmaxf(m, s[qs][2][1]), s[qs][2][2]);
            m = fmaxf(fmaxf(m, s[qs][2][3]), s[qs][3][0]);
            m = fmaxf(fmaxf(m, s[qs][3][1]), s[qs][3][2]);
            m = fmaxf(m, s[qs][3][3]);
            m = fmaxf(m, __shfl_xor(m, 16));
            m = fmaxf(m, __shfl_xor(m, 32));
            mx[qs] = m * QSCALE;
        }

        // combined defer-max check; rescale both sub-blocks when triggered
        if (!__all(mx[0] <= m_run[0] + 8.0f && mx[1] <= m_run[1] + 8.0f)) {
#pragma unroll
            for (int qs = 0; qs < 2; ++qs) {
                const float mn = fmaxf(m_run[qs], mx[qs]);
                const float alpha = exp2f(m_run[qs] - mn);
                m_run[qs] = mn;
                const float a0 = __shfl(alpha, l4 * 4 + 0);
                const float a1 = __shfl(alpha, l4 * 4 + 1);
                const float a2 = __shfl(alpha, l4 * 4 + 2);
                const float a3 = __shfl(alpha, l4 * 4 + 3);
#pragma unroll
                for (int df = 0; df < 4; ++df) {
                    o[qs][df][0] *= a0; o[qs][df][1] *= a1;
                    o[qs][df][2] *= a2; o[qs][df][3] *= a3;
                }
                accl[qs][0] *= a0; accl[qs][1] *= a1;
                accl[qs][2] *= a2; accl[qs][3] *= a3;
            }
        }

        // P = exp2(QSCALE*s - m), packed to per-(wave,sub-block) LDS regions
#pragma unroll
        for (int qs = 0; qs < 2; ++qs) {
            unsigned short* Pw = &lP[w][qs][0];
#pragma unroll
            for (int nf = 0; nf < 4; ++nf) {
                const float p0 = exp2f(fmaf(s[qs][nf][0], QSCALE, -m_run[qs]));
                const float p1 = exp2f(fmaf(s[qs][nf][1], QSCALE, -m_run[qs]));
                const float p2 = exp2f(fmaf(s[qs][nf][2], QSCALE, -m_run[qs]));
                const float p3 = exp2f(fmaf(s[qs][nf][3], QSCALE, -m_run[qs]));
                union { unsigned int d[2]; uint64_t q; } u;
                u.d[0] = cvt_pk_bf16(p0, p1);
                u.d[1] = cvt_pk_bf16(p2, p3);
                *(uint64_t*)(Pw + offPw[nf]) = u.q;
            }
        }

        // P A-frags (2 per sub-block), then PV with V B-frags read ONCE
        bf16x8 ap[2][2];
#pragma unroll
        for (int qs = 0; qs < 2; ++qs) {
            unsigned short* Pw = &lP[w][qs][0];
            ap[qs][0] = *(const bf16x8*)(Pw + l15 * 64 + ((l4 ^ (l15 & 7)) << 3));
            ap[qs][1] = *(const bf16x8*)(Pw + l15 * 64 + (((4 + l4) ^ (l15 & 7)) << 3));
        }
        __builtin_amdgcn_s_setprio(1);
#pragma unroll
        for (int qs = 0; qs < 2; ++qs) {
            accl[qs] = __builtin_amdgcn_mfma_f32_16x16x32_bf16(ap[qs][0], ones8, accl[qs], 0, 0, 0);
            accl[qs] = __builtin_amdgcn_mfma_f32_16x16x32_bf16(ap[qs][1], ones8, accl[qs], 0, 0, 0);
        }
#pragma unroll
        for (int df = 0; df < 4; ++df) {
            const int r = df * 16 + l15;
            const bf16x8 bv0 = *(const bf16x8*)(V + r * 64 + ((l4 ^ (r & 7)) << 3));
            const bf16x8 bv1 = *(const bf16x8*)(V + r * 64 + (((4 + l4) ^ (r & 7)) << 3));
#pragma unroll
            for (int qs = 0; qs < 2; ++qs) {
                o[qs][df] = __builtin_amdgcn_mfma_f32_16x16x32_bf16(ap[qs][0], bv0, o[qs][df], 0, 0, 0);
                o[qs][df] = __builtin_amdgcn_mfma_f32_16x16x32_bf16(ap[qs][1], bv1, o[qs][df], 0, 0, 0);
            }
        }
        __builtin_amdgcn_s_setprio(0);

        if (more) {
#pragma unroll
            for (int p = 0; p < 2; ++p) {
                *(bf16x8*)(&lK[cur ^ 1][0] + p * 32 * 64 + swoff) = rk[p];
                *(bf16x8*)(&lV[cur ^ 1][0] + p * 32 * 64 + swoff) = rv[p];
            }
        }
        __syncthreads();
    }

    // epilogue
#pragma unroll
    for (int qs = 0; qs < 2; ++qs) {
        const float r0 = 1.0f / accl[qs][0];
        const float r1 = 1.0f / accl[qs][1];
        const float r2 = 1.0f / accl[qs][2];
        const float r3 = 1.0f / accl[qs][3];
        const int rowb = b * 2048 + qb + w * 32 + qs * 16 + l4 * 4;
#pragma unroll
        for (int df = 0; df < 4; ++df) {
            const int d = df * 16 + l15;
            attn_out[(size_t)(rowb + 0) * 1024 + h * 64 + d] = f2bf(o[qs][df][0] * r0);
            attn_out[(size_t)(rowb + 1) * 1024 + h * 64 + d] = f2bf(o[qs][df][1] * r1);
            attn_out[(size_t)(rowb + 2) * 1024 + h * 64 + d] = f2bf(o[qs][df][2] * r2);
            attn_out[(size_t)(rowb + 3) * 1024 + h * 64 + d] = f2bf(o[qs][df][3] * r3);
        }
    }
}

// ---------------------------------------------------------------------------
extern "C" void kernel_launch(void* const* d_in, const int* in_sizes, int n_in,
                              void* d_out, int out_size, void* d_ws, size_t ws_size,
                              hipStream_t stream) {
    const float* x      = (const float*)d_in[0];
    const float* w_qkv  = (const float*)d_in[1];
    const float* w_proj = (const float*)d_in[2];
    const float* b_proj = (const float*)d_in[3];
    float* out = (float*)d_out;

    char* ws = (char*)d_ws;
    unsigned short* xb     = (unsigned short*)(ws + 0);           //  8M
    unsigned short* wqkvT  = (unsigned short*)(ws + 8388608);     //  6M
    unsigned short* wprojT = (unsigned short*)(ws + 14680064);    //  2M
    unsigned short* qkv    = (unsigned short*)(ws + 16777216);    // 24M
    unsigned short* vt     = (unsigned short*)(ws + 41943040);    //  8M
    unsigned short* attn   = (unsigned short*)(ws + 50331648);    //  8M

    k_cvt_x<<<dim3(4096), dim3(256), 0, stream>>>(x, xb, 4096 * 1024 / 4);
    k_cvt_tr_w<<<dim3(48, 16), dim3(256), 0, stream>>>(w_qkv, wqkvT, 1024, 3072);
    k_cvt_tr_w<<<dim3(16, 16), dim3(256), 0, stream>>>(w_proj, wprojT, 1024, 1024);
    k_gemm_bt<1, 128><<<dim3(24, 32), dim3(256), 0, stream>>>(xb, wqkvT, (void*)qkv, (const float*)nullptr, vt, 4096, 3072, 1024);
    k_attn<<<dim3(16, 32), dim3(256), 0, stream>>>(qkv, vt, attn);
    k_gemm_bt<0, 64><<<dim3(16, 32), dim3(256), 0, stream>>>(attn, wprojT, (void*)out, b_proj, (unsigned short*)nullptr, 4096, 1024, 1024);
}

// Round 11
// 130.781 us; speedup vs baseline: 1.0258x; 1.0258x over previous
//
#include <hip/hip_runtime.h>
#include <stdint.h>

typedef __attribute__((ext_vector_type(8))) short bf16x8;
typedef __attribute__((ext_vector_type(4))) float f32x4;
typedef __attribute__((ext_vector_type(4))) float float4v;
typedef __attribute__((ext_vector_type(8))) unsigned short u16x8;

#define DEV __device__ __forceinline__

DEV unsigned short f2bf(float f) {
    union { float f; uint32_t u; } v; v.f = f;
    uint32_t u = v.u;
    return (unsigned short)((u + 0x7FFFu + ((u >> 16) & 1u)) >> 16);
}

DEV unsigned int cvt_pk_bf16(float lo, float hi) {
    unsigned int r;
    asm("v_cvt_pk_bf16_f32 %0, %1, %2" : "=v"(r) : "v"(lo), "v"(hi));
    return r;
}

#if __has_builtin(__builtin_amdgcn_global_load_lds)
#define HAVE_GLDS 1
typedef const unsigned char __attribute__((address_space(1)))* as1p;
typedef unsigned char __attribute__((address_space(3)))* as3p;
DEV void gload16(const unsigned short* g, unsigned short* l) {
    __builtin_amdgcn_global_load_lds((as1p)(const void*)g, (as3p)(void*)l, 16, 0, 0);
}
#else
#define HAVE_GLDS 0
#endif

// ---------------------------------------------------------------------------
// 1) fp32 -> bf16 convert (x)
// ---------------------------------------------------------------------------
__global__ void k_cvt_x(const float* __restrict__ x, unsigned short* __restrict__ xb, int n4) {
    int i = blockIdx.x * blockDim.x + threadIdx.x;
    if (i >= n4) return;
    float4v v = *(const float4v*)(x + (size_t)i * 4);
    union { unsigned short s[4]; uint64_t q; } o;
    o.s[0] = f2bf(v[0]); o.s[1] = f2bf(v[1]); o.s[2] = f2bf(v[2]); o.s[3] = f2bf(v[3]);
    *(uint64_t*)(xb + (size_t)i * 4) = o.q;
}

// ---------------------------------------------------------------------------
// 2) fp32 [R][C] -> bf16 [C][R] convert + transpose
// ---------------------------------------------------------------------------
__global__ void k_cvt_tr_w(const float* __restrict__ w, unsigned short* __restrict__ wt,
                           int R, int C) {
    __shared__ alignas(16) unsigned short tile[64][65];
    const int t = threadIdx.x;
    const int tr = blockIdx.y * 64, tc = blockIdx.x * 64;
#pragma unroll
    for (int p = 0; p < 4; ++p) {
        int r = p * 16 + (t >> 4);
        int c = (t & 15) * 4;
        float4v v = *(const float4v*)(w + (size_t)(tr + r) * C + tc + c);
#pragma unroll
        for (int j = 0; j < 4; ++j) tile[r][c + j] = f2bf(v[j]);
    }
    __syncthreads();
#pragma unroll
    for (int p = 0; p < 2; ++p) {
        int r2 = p * 32 + (t >> 3);
        int k0 = (t & 7) * 8;
        u16x8 o;
#pragma unroll
        for (int j = 0; j < 8; ++j) o[j] = tile[k0 + j][r2];
        *(u16x8*)(wt + (size_t)(tc + r2) * R + tr + k0) = o;
    }
}

// ---------------------------------------------------------------------------
// 3) bf16 GEMM: C[M,N] = A[M,K] * Bt[N,K]^T.  Tile BM x BN, BK=64, 4 waves
//    (2x2 wave grid, each wave BM/2 x BN/2).  BM/BN in {64,128}.
//    proj uses 64x64 -> grid 1024 = 4 blocks/CU = 16 waves/CU (occupancy
//    lesson from R9/R10: this wave count carries the latency hiding).
//    GLDS(16B) staging, pre-swizzled source; fused V-transpose epilogue.
// ---------------------------------------------------------------------------
template <int OUT_BF16, int BM, int BN>
__global__ __launch_bounds__(256)
void k_gemm_bt(const unsigned short* __restrict__ A,
               const unsigned short* __restrict__ Bt,
               void* __restrict__ Cp, const float* __restrict__ bias,
               unsigned short* __restrict__ vt_out,
               int M, int N, int K) {
    constexpr int MFR = BM / 32;          // M frags per wave
    constexpr int NFR = BN / 32;          // N frags per wave
    __shared__ alignas(16) unsigned short lA[BM * 64];
    __shared__ alignas(16) unsigned short lB[BN * 64];
    const int t = threadIdx.x;
    const int w = t >> 6, l = t & 63;
    const int l15 = l & 15, l4 = l >> 4;
    const int wm = (w >> 1) * (BM / 2), wn = (w & 1) * (BN / 2);
    const size_t bm = (size_t)blockIdx.y * BM, bn = (size_t)blockIdx.x * BN;

    int offA[MFR][2], offB[NFR][2];
#pragma unroll
    for (int f = 0; f < MFR; ++f) {
        const int ra = wm + f * 16 + l15;
#pragma unroll
        for (int kc = 0; kc < 2; ++kc)
            offA[f][kc] = ra * 64 + (((kc * 4 + l4) ^ (ra & 7)) << 3);
    }
#pragma unroll
    for (int f = 0; f < NFR; ++f) {
        const int rb = wn + f * 16 + l15;
#pragma unroll
        for (int kc = 0; kc < 2; ++kc)
            offB[f][kc] = rb * 64 + (((kc * 4 + l4) ^ (rb & 7)) << 3);
    }

#if HAVE_GLDS
    const int srow8 = l >> 3;
    const int scol  = (l & 7) ^ srow8;
    const unsigned short* gA = A  + (bm + w * (BM / 4) + srow8) * (size_t)K + scol * 8;
    const unsigned short* gB = Bt + (bn + w * (BN / 4) + srow8) * (size_t)K + scol * 8;
    unsigned short* dA = lA + (w * (BM / 4)) * 64;
    unsigned short* dB = lB + (w * (BN / 4)) * 64;
#else
    const int srow = t >> 3, sslot = t & 7;
    const int swoff = srow * 64 + ((sslot ^ (srow & 7)) << 3);
    const unsigned short* pA = A + (bm + srow) * (size_t)K + sslot * 8;
    const unsigned short* pB = Bt + (bn + srow) * (size_t)K + sslot * 8;
#endif

    const f32x4 zf = {0.f, 0.f, 0.f, 0.f};
    f32x4 acc[MFR][NFR];
#pragma unroll
    for (int i = 0; i < MFR; ++i)
#pragma unroll
        for (int j = 0; j < NFR; ++j) acc[i][j] = zf;

    for (int kt = 0; kt < K; kt += 64) {
#if HAVE_GLDS
        __syncthreads();
#pragma unroll
        for (int i = 0; i < BM / 32; ++i)
            gload16(gA + (size_t)i * 8 * K + kt, dA + i * 8 * 64);
#pragma unroll
        for (int i = 0; i < BN / 32; ++i)
            gload16(gB + (size_t)i * 8 * K + kt, dB + i * 8 * 64);
        __syncthreads();
#else
        bf16x8 ra[BM / 32], rb[BN / 32];
#pragma unroll
        for (int p = 0; p < BM / 32; ++p)
            ra[p] = *(const bf16x8*)(pA + (size_t)p * 32 * K + kt);
#pragma unroll
        for (int p = 0; p < BN / 32; ++p)
            rb[p] = *(const bf16x8*)(pB + (size_t)p * 32 * K + kt);
        __syncthreads();
#pragma unroll
        for (int p = 0; p < BM / 32; ++p)
            *(bf16x8*)(lA + p * 32 * 64 + swoff) = ra[p];
#pragma unroll
        for (int p = 0; p < BN / 32; ++p)
            *(bf16x8*)(lB + p * 32 * 64 + swoff) = rb[p];
        __syncthreads();
#endif
#pragma unroll
        for (int kc = 0; kc < 2; ++kc) {
            bf16x8 af[MFR], bfr[NFR];
#pragma unroll
            for (int f = 0; f < MFR; ++f) af[f] = *(const bf16x8*)(lA + offA[f][kc]);
#pragma unroll
            for (int f = 0; f < NFR; ++f) bfr[f] = *(const bf16x8*)(lB + offB[f][kc]);
#pragma unroll
            for (int mf = 0; mf < MFR; ++mf)
#pragma unroll
                for (int nf = 0; nf < NFR; ++nf)
                    acc[mf][nf] = __builtin_amdgcn_mfma_f32_16x16x32_bf16(
                        af[mf], bfr[nf], acc[mf][nf], 0, 0, 0);
        }
    }

    if (OUT_BF16) {
        if (vt_out && bn >= 2048) {
            const int bb = (int)(bm >> 11);
            const int n0 = (int)(bm & 2047) + wm + l4 * 4;
#pragma unroll
            for (int nf = 0; nf < NFR; ++nf) {
                const int d = (int)(bn - 2048) + wn + nf * 16 + l15;
                unsigned short* vrow = vt_out + ((size_t)(bb * 16 + (d >> 6)) * 64 + (d & 63)) * 2048;
#pragma unroll
                for (int mf = 0; mf < MFR; ++mf) {
                    union { unsigned short s[4]; uint64_t q; } u;
#pragma unroll
                    for (int j = 0; j < 4; ++j) u.s[j] = f2bf(acc[mf][nf][j]);
                    *(uint64_t*)(vrow + n0 + mf * 16) = u.q;
                }
            }
        } else {
            unsigned short* C = (unsigned short*)Cp;
#pragma unroll
            for (int mf = 0; mf < MFR; ++mf)
#pragma unroll
                for (int nf = 0; nf < NFR; ++nf) {
                    const size_t row = bm + wm + mf * 16 + l4 * 4;
                    const size_t col = bn + wn + nf * 16 + l15;
#pragma unroll
                    for (int j = 0; j < 4; ++j)
                        C[(row + j) * (size_t)N + col] = f2bf(acc[mf][nf][j]);
                }
        }
    } else {
        float* C = (float*)Cp;
#pragma unroll
        for (int nf = 0; nf < NFR; ++nf) {
            const size_t col = bn + wn + nf * 16 + l15;
            const float bv = bias[col];
#pragma unroll
            for (int mf = 0; mf < MFR; ++mf) {
                const size_t row = bm + wm + mf * 16 + l4 * 4;
#pragma unroll
                for (int j = 0; j < 4; ++j)
                    C[(row + j) * (size_t)N + col] = acc[mf][nf][j] + bv;
            }
        }
    }
}

// ---------------------------------------------------------------------------
// 5) Flash attention — R9-exact (the proven optimum: 4 blocks/CU, 16
//    waves/CU, reg-staged dbuf, 1 barrier/iter, defer-max, MFMA ones-rowsum,
//    setprio). R10's 32q/wave variant reverted (occupancy loss beat the
//    LDS-reuse gain; kernel is latency-bound, needs the TLP).
// ---------------------------------------------------------------------------
__global__ __launch_bounds__(256, 4)
void k_attn(const unsigned short* __restrict__ qkv, const unsigned short* __restrict__ vt,
            unsigned short* __restrict__ attn_out) {
    __shared__ alignas(16) unsigned short lK[2][64 * 64];
    __shared__ alignas(16) unsigned short lV[2][64 * 64];
    __shared__ alignas(16) unsigned short lP[4][16 * 64];
    const int t = threadIdx.x, w = t >> 6, l = t & 63;
    const int l15 = l & 15, l4 = l >> 4;
    const int bh = blockIdx.y, b = bh >> 4, h = bh & 15;
    const int qb = blockIdx.x * 64;
    const float QSCALE = 0.18033688011112042f;   // 0.125 * log2(e)

    const unsigned short* qptr =
        qkv + (size_t)(b * 2048 + qb + w * 16 + l15) * 3072 + h * 64 + l4 * 8;
    const bf16x8 aq0 = *(const bf16x8*)(qptr);
    const bf16x8 aq1 = *(const bf16x8*)(qptr + 32);

    const int srow = t >> 3, sslot = t & 7;
    const int swoff = srow * 64 + ((sslot ^ (srow & 7)) << 3);
    const unsigned short* kptr = qkv + (size_t)(b * 2048 + srow) * 3072 + 1024 + h * 64 + sslot * 8;
    const unsigned short* vptr = vt + (size_t)(bh * 64 + srow) * 2048 + sslot * 8;

    int offK[4][2];
#pragma unroll
    for (int nf = 0; nf < 4; ++nf) {
        const int r = nf * 16 + l15;
#pragma unroll
        for (int kc = 0; kc < 2; ++kc)
            offK[nf][kc] = r * 64 + (((kc * 4 + l4) ^ (r & 7)) << 3);
    }
    int offPw[4];
#pragma unroll
    for (int nf = 0; nf < 4; ++nf) {
        const int c = nf * 16 + l4 * 4;
        offPw[nf] = l15 * 64 + (((c >> 3) ^ (l15 & 7)) << 3) + (c & 7);
    }

    const f32x4 zf = {0.f, 0.f, 0.f, 0.f};
    f32x4 o[4];
#pragma unroll
    for (int df = 0; df < 4; ++df) o[df] = zf;
    f32x4 accl = zf;
    float m_run = -1e30f;
    unsigned short* Pw = &lP[w][0];
    const bf16x8 ones8 = {(short)0x3F80, (short)0x3F80, (short)0x3F80, (short)0x3F80,
                          (short)0x3F80, (short)0x3F80, (short)0x3F80, (short)0x3F80};

    // prologue: stage tile 0 into buffer 0
    {
        bf16x8 rk[2], rv[2];
#pragma unroll
        for (int p = 0; p < 2; ++p) {
            rk[p] = *(const bf16x8*)(kptr + (size_t)(p * 32) * 3072);
            rv[p] = *(const bf16x8*)(vptr + (size_t)(p * 32) * 2048);
        }
#pragma unroll
        for (int p = 0; p < 2; ++p) {
            *(bf16x8*)(&lK[0][0] + p * 32 * 64 + swoff) = rk[p];
            *(bf16x8*)(&lV[0][0] + p * 32 * 64 + swoff) = rv[p];
        }
        __syncthreads();
    }

#pragma unroll 2
    for (int kt = 0; kt < 2048; kt += 64) {
        const int cur = (kt >> 6) & 1;
        const unsigned short* K = &lK[cur][0];
        const unsigned short* V = &lV[cur][0];

        bf16x8 rk[2], rv[2];
        const bool more = (kt + 64) < 2048;
        if (more) {
#pragma unroll
            for (int p = 0; p < 2; ++p) {
                rk[p] = *(const bf16x8*)(kptr + (size_t)(kt + 64 + p * 32) * 3072);
                rv[p] = *(const bf16x8*)(vptr + (size_t)(p * 32) * 2048 + kt + 64);
            }
        }

        // S^T = K Q^T : lane holds S_raw[kv = nf*16 + l4*4 + j][q = l15]
        f32x4 s[4];
        __builtin_amdgcn_s_setprio(1);
#pragma unroll
        for (int nf = 0; nf < 4; ++nf) {
            const bf16x8 kf0 = *(const bf16x8*)(K + offK[nf][0]);
            const bf16x8 kf1 = *(const bf16x8*)(K + offK[nf][1]);
            f32x4 a = zf;
            a = __builtin_amdgcn_mfma_f32_16x16x32_bf16(kf0, aq0, a, 0, 0, 0);
            a = __builtin_amdgcn_mfma_f32_16x16x32_bf16(kf1, aq1, a, 0, 0, 0);
            s[nf] = a;
        }
        __builtin_amdgcn_s_setprio(0);

        // row max over 16 lane-local values + 2 shfl across the 4 dup lanes
        float mx = fmaxf(fmaxf(s[0][0], s[0][1]), s[0][2]);
        mx = fmaxf(fmaxf(mx, s[0][3]), s[1][0]);
        mx = fmaxf(fmaxf(mx, s[1][1]), s[1][2]);
        mx = fmaxf(fmaxf(mx, s[1][3]), s[2][0]);
        mx = fmaxf(fmaxf(mx, s[2][1]), s[2][2]);
        mx = fmaxf(fmaxf(mx, s[2][3]), s[3][0]);
        mx = fmaxf(fmaxf(mx, s[3][1]), s[3][2]);
        mx = fmaxf(mx, s[3][3]);
        mx = fmaxf(mx, __shfl_xor(mx, 16));
        mx = fmaxf(mx, __shfl_xor(mx, 32));
        mx *= QSCALE;

        // defer-max: rescale only when the row max grew by > 8 (log2 domain)
        if (!__all(mx <= m_run + 8.0f)) {
            const float mn = fmaxf(m_run, mx);
            const float alpha = exp2f(m_run - mn);
            m_run = mn;
            const float a0 = __shfl(alpha, l4 * 4 + 0);
            const float a1 = __shfl(alpha, l4 * 4 + 1);
            const float a2 = __shfl(alpha, l4 * 4 + 2);
            const float a3 = __shfl(alpha, l4 * 4 + 3);
#pragma unroll
            for (int df = 0; df < 4; ++df) {
                o[df][0] *= a0; o[df][1] *= a1; o[df][2] *= a2; o[df][3] *= a3;
            }
            accl[0] *= a0; accl[1] *= a1; accl[2] *= a2; accl[3] *= a3;
        }

        // P = exp2(QSCALE*s_raw - m), packed to per-wave LDS (b64 writes)
#pragma unroll
        for (int nf = 0; nf < 4; ++nf) {
            const float p0 = exp2f(fmaf(s[nf][0], QSCALE, -m_run));
            const float p1 = exp2f(fmaf(s[nf][1], QSCALE, -m_run));
            const float p2 = exp2f(fmaf(s[nf][2], QSCALE, -m_run));
            const float p3 = exp2f(fmaf(s[nf][3], QSCALE, -m_run));
            union { unsigned int d[2]; uint64_t q; } u;
            u.d[0] = cvt_pk_bf16(p0, p1);
            u.d[1] = cvt_pk_bf16(p2, p3);
            *(uint64_t*)(Pw + offPw[nf]) = u.q;
        }

        // O += P V ; rowsum via ones-column on the MFMA pipe
        const bf16x8 ap0 = *(const bf16x8*)(Pw + l15 * 64 + ((l4 ^ (l15 & 7)) << 3));
        const bf16x8 ap1 = *(const bf16x8*)(Pw + l15 * 64 + (((4 + l4) ^ (l15 & 7)) << 3));
        __builtin_amdgcn_s_setprio(1);
        accl = __builtin_amdgcn_mfma_f32_16x16x32_bf16(ap0, ones8, accl, 0, 0, 0);
        accl = __builtin_amdgcn_mfma_f32_16x16x32_bf16(ap1, ones8, accl, 0, 0, 0);
#pragma unroll
        for (int df = 0; df < 4; ++df) {
            const int r = df * 16 + l15;
            const bf16x8 bv0 = *(const bf16x8*)(V + r * 64 + ((l4 ^ (r & 7)) << 3));
            const bf16x8 bv1 = *(const bf16x8*)(V + r * 64 + (((4 + l4) ^ (r & 7)) << 3));
            o[df] = __builtin_amdgcn_mfma_f32_16x16x32_bf16(ap0, bv0, o[df], 0, 0, 0);
            o[df] = __builtin_amdgcn_mfma_f32_16x16x32_bf16(ap1, bv1, o[df], 0, 0, 0);
        }
        __builtin_amdgcn_s_setprio(0);

        if (more) {
#pragma unroll
            for (int p = 0; p < 2; ++p) {
                *(bf16x8*)(&lK[cur ^ 1][0] + p * 32 * 64 + swoff) = rk[p];
                *(bf16x8*)(&lV[cur ^ 1][0] + p * 32 * 64 + swoff) = rv[p];
            }
        }
        __syncthreads();
    }

    // epilogue: O / l  (accl rows aligned with o rows -> no shuffles)
    const float r0 = 1.0f / accl[0];
    const float r1 = 1.0f / accl[1];
    const float r2 = 1.0f / accl[2];
    const float r3 = 1.0f / accl[3];
    const int rowb = b * 2048 + qb + w * 16 + l4 * 4;
#pragma unroll
    for (int df = 0; df < 4; ++df) {
        const int d = df * 16 + l15;
        attn_out[(size_t)(rowb + 0) * 1024 + h * 64 + d] = f2bf(o[df][0] * r0);
        attn_out[(size_t)(rowb + 1) * 1024 + h * 64 + d] = f2bf(o[df][1] * r1);
        attn_out[(size_t)(rowb + 2) * 1024 + h * 64 + d] = f2bf(o[df][2] * r2);
        attn_out[(size_t)(rowb + 3) * 1024 + h * 64 + d] = f2bf(o[df][3] * r3);
    }
}

// ---------------------------------------------------------------------------
extern "C" void kernel_launch(void* const* d_in, const int* in_sizes, int n_in,
                              void* d_out, int out_size, void* d_ws, size_t ws_size,
                              hipStream_t stream) {
    const float* x      = (const float*)d_in[0];
    const float* w_qkv  = (const float*)d_in[1];
    const float* w_proj = (const float*)d_in[2];
    const float* b_proj = (const float*)d_in[3];
    float* out = (float*)d_out;

    char* ws = (char*)d_ws;
    unsigned short* xb     = (unsigned short*)(ws + 0);           //  8M
    unsigned short* wqkvT  = (unsigned short*)(ws + 8388608);     //  6M
    unsigned short* wprojT = (unsigned short*)(ws + 14680064);    //  2M
    unsigned short* qkv    = (unsigned short*)(ws + 16777216);    // 24M
    unsigned short* vt     = (unsigned short*)(ws + 41943040);    //  8M
    unsigned short* attn   = (unsigned short*)(ws + 50331648);    //  8M

    k_cvt_x<<<dim3(4096), dim3(256), 0, stream>>>(x, xb, 4096 * 1024 / 4);
    k_cvt_tr_w<<<dim3(48, 16), dim3(256), 0, stream>>>(w_qkv, wqkvT, 1024, 3072);
    k_cvt_tr_w<<<dim3(16, 16), dim3(256), 0, stream>>>(w_proj, wprojT, 1024, 1024);
    k_gemm_bt<1, 128, 128><<<dim3(24, 32), dim3(256), 0, stream>>>(xb, wqkvT, (void*)qkv, (const float*)nullptr, vt, 4096, 3072, 1024);
    k_attn<<<dim3(32, 32), dim3(256), 0, stream>>>(qkv, vt, attn);
    k_gemm_bt<0, 64, 64><<<dim3(16, 64), dim3(256), 0, stream>>>(attn, wprojT, (void*)out, b_proj, (unsigned short*)nullptr, 4096, 1024, 1024);
}

// Round 12
// 128.175 us; speedup vs baseline: 1.0467x; 1.0203x over previous
//
#include <hip/hip_runtime.h>
#include <stdint.h>

typedef __attribute__((ext_vector_type(8))) short bf16x8;
typedef __attribute__((ext_vector_type(4))) float f32x4;
typedef __attribute__((ext_vector_type(4))) float float4v;
typedef __attribute__((ext_vector_type(8))) unsigned short u16x8;

#define DEV __device__ __forceinline__

DEV unsigned short f2bf(float f) {
    union { float f; uint32_t u; } v; v.f = f;
    uint32_t u = v.u;
    return (unsigned short)((u + 0x7FFFu + ((u >> 16) & 1u)) >> 16);
}

DEV unsigned int cvt_pk_bf16(float lo, float hi) {
    unsigned int r;
    asm("v_cvt_pk_bf16_f32 %0, %1, %2" : "=v"(r) : "v"(lo), "v"(hi));
    return r;
}

#if __has_builtin(__builtin_amdgcn_global_load_lds)
#define HAVE_GLDS 1
typedef const unsigned char __attribute__((address_space(1)))* as1p;
typedef unsigned char __attribute__((address_space(3)))* as3p;
DEV void gload16(const unsigned short* g, unsigned short* l) {
    __builtin_amdgcn_global_load_lds((as1p)(const void*)g, (as3p)(void*)l, 16, 0, 0);
}
#else
#define HAVE_GLDS 0
#endif

// ---------------------------------------------------------------------------
// 1+2) fused converts: one dispatch, branch by block range.
//   blocks [0,4096)      : x fp32 -> bf16 (xb)
//   blocks [4096,4864)   : w_qkv fp32 [1024][3072] -> bf16 [3072][1024] (wqkvT)
//   blocks [4864,5120)   : w_proj fp32 [1024][1024] -> bf16 [1024][1024]^T
// ---------------------------------------------------------------------------
__global__ void k_cvt_all(const float* __restrict__ x, unsigned short* __restrict__ xb,
                          const float* __restrict__ wqkv, unsigned short* __restrict__ wqkvT,
                          const float* __restrict__ wproj, unsigned short* __restrict__ wprojT) {
    __shared__ alignas(16) unsigned short tile[64][65];
    const int blk = blockIdx.x;
    const int t = threadIdx.x;
    if (blk < 4096) {
        const int i = blk * 256 + t;
        float4v v = *(const float4v*)(x + (size_t)i * 4);
        union { unsigned short s[4]; uint64_t q; } o;
        o.s[0] = f2bf(v[0]); o.s[1] = f2bf(v[1]); o.s[2] = f2bf(v[2]); o.s[3] = f2bf(v[3]);
        *(uint64_t*)(xb + (size_t)i * 4) = o.q;
        return;
    }
    const float* w; unsigned short* wt; int R, C, bx, by;
    if (blk < 4864) {
        const int b2 = blk - 4096;
        w = wqkv; wt = wqkvT; R = 1024; C = 3072;
        bx = b2 % 48; by = b2 / 48;
    } else {
        const int b3 = blk - 4864;
        w = wproj; wt = wprojT; R = 1024; C = 1024;
        bx = b3 % 16; by = b3 / 16;
    }
    const int tr = by * 64, tc = bx * 64;
#pragma unroll
    for (int p = 0; p < 4; ++p) {
        int r = p * 16 + (t >> 4);
        int c = (t & 15) * 4;
        float4v v = *(const float4v*)(w + (size_t)(tr + r) * C + tc + c);
#pragma unroll
        for (int j = 0; j < 4; ++j) tile[r][c + j] = f2bf(v[j]);
    }
    __syncthreads();
#pragma unroll
    for (int p = 0; p < 2; ++p) {
        int r2 = p * 32 + (t >> 3);
        int k0 = (t & 7) * 8;
        u16x8 o;
#pragma unroll
        for (int j = 0; j < 8; ++j) o[j] = tile[k0 + j][r2];
        *(u16x8*)(wt + (size_t)(tc + r2) * R + tr + k0) = o;
    }
}

// ---------------------------------------------------------------------------
// 3) bf16 GEMM: C[M,N] = A[M,K] * Bt[N,K]^T.  Tile BM x BN, BK=64, 4 waves.
//    1D grid + XCD-aware swizzle (T1): work = (bid%8)*cpx + bid/8, decoded
//    n-tile-major (bx = work/NTY) so each XCD owns a contiguous group of
//    B-panels (L2-resident) while A streams. NTY = # m-tiles (template).
//    GLDS(16B) staging, pre-swizzled source; fused V-transpose epilogue.
// ---------------------------------------------------------------------------
template <int OUT_BF16, int BM, int BN, int NTY>
__global__ __launch_bounds__(256)
void k_gemm_bt(const unsigned short* __restrict__ A,
               const unsigned short* __restrict__ Bt,
               void* __restrict__ Cp, const float* __restrict__ bias,
               unsigned short* __restrict__ vt_out,
               int M, int N, int K) {
    constexpr int MFR = BM / 32;
    constexpr int NFR = BN / 32;
    __shared__ alignas(16) unsigned short lA[BM * 64];
    __shared__ alignas(16) unsigned short lB[BN * 64];
    const int t = threadIdx.x;
    const int w = t >> 6, l = t & 63;
    const int l15 = l & 15, l4 = l >> 4;
    const int wm = (w >> 1) * (BM / 2), wn = (w & 1) * (BN / 2);

    // XCD swizzle: nwg % 8 == 0 guaranteed by launch config
    const int cpx = gridDim.x >> 3;
    const int wk = (blockIdx.x & 7) * cpx + (blockIdx.x >> 3);
    const int bx = wk / NTY, by = wk % NTY;
    const size_t bm = (size_t)by * BM, bn = (size_t)bx * BN;

    int offA[MFR][2], offB[NFR][2];
#pragma unroll
    for (int f = 0; f < MFR; ++f) {
        const int ra = wm + f * 16 + l15;
#pragma unroll
        for (int kc = 0; kc < 2; ++kc)
            offA[f][kc] = ra * 64 + (((kc * 4 + l4) ^ (ra & 7)) << 3);
    }
#pragma unroll
    for (int f = 0; f < NFR; ++f) {
        const int rb = wn + f * 16 + l15;
#pragma unroll
        for (int kc = 0; kc < 2; ++kc)
            offB[f][kc] = rb * 64 + (((kc * 4 + l4) ^ (rb & 7)) << 3);
    }

#if HAVE_GLDS
    const int srow8 = l >> 3;
    const int scol  = (l & 7) ^ srow8;
    const unsigned short* gA = A  + (bm + w * (BM / 4) + srow8) * (size_t)K + scol * 8;
    const unsigned short* gB = Bt + (bn + w * (BN / 4) + srow8) * (size_t)K + scol * 8;
    unsigned short* dA = lA + (w * (BM / 4)) * 64;
    unsigned short* dB = lB + (w * (BN / 4)) * 64;
#else
    const int srow = t >> 3, sslot = t & 7;
    const int swoff = srow * 64 + ((sslot ^ (srow & 7)) << 3);
    const unsigned short* pA = A + (bm + srow) * (size_t)K + sslot * 8;
    const unsigned short* pB = Bt + (bn + srow) * (size_t)K + sslot * 8;
#endif

    const f32x4 zf = {0.f, 0.f, 0.f, 0.f};
    f32x4 acc[MFR][NFR];
#pragma unroll
    for (int i = 0; i < MFR; ++i)
#pragma unroll
        for (int j = 0; j < NFR; ++j) acc[i][j] = zf;

    for (int kt = 0; kt < K; kt += 64) {
#if HAVE_GLDS
        __syncthreads();
#pragma unroll
        for (int i = 0; i < BM / 32; ++i)
            gload16(gA + (size_t)i * 8 * K + kt, dA + i * 8 * 64);
#pragma unroll
        for (int i = 0; i < BN / 32; ++i)
            gload16(gB + (size_t)i * 8 * K + kt, dB + i * 8 * 64);
        __syncthreads();
#else
        bf16x8 ra[BM / 32], rb[BN / 32];
#pragma unroll
        for (int p = 0; p < BM / 32; ++p)
            ra[p] = *(const bf16x8*)(pA + (size_t)p * 32 * K + kt);
#pragma unroll
        for (int p = 0; p < BN / 32; ++p)
            rb[p] = *(const bf16x8*)(pB + (size_t)p * 32 * K + kt);
        __syncthreads();
#pragma unroll
        for (int p = 0; p < BM / 32; ++p)
            *(bf16x8*)(lA + p * 32 * 64 + swoff) = ra[p];
#pragma unroll
        for (int p = 0; p < BN / 32; ++p)
            *(bf16x8*)(lB + p * 32 * 64 + swoff) = rb[p];
        __syncthreads();
#endif
#pragma unroll
        for (int kc = 0; kc < 2; ++kc) {
            bf16x8 af[MFR], bfr[NFR];
#pragma unroll
            for (int f = 0; f < MFR; ++f) af[f] = *(const bf16x8*)(lA + offA[f][kc]);
#pragma unroll
            for (int f = 0; f < NFR; ++f) bfr[f] = *(const bf16x8*)(lB + offB[f][kc]);
#pragma unroll
            for (int mf = 0; mf < MFR; ++mf)
#pragma unroll
                for (int nf = 0; nf < NFR; ++nf)
                    acc[mf][nf] = __builtin_amdgcn_mfma_f32_16x16x32_bf16(
                        af[mf], bfr[nf], acc[mf][nf], 0, 0, 0);
        }
    }

    if (OUT_BF16) {
        if (vt_out && bn >= 2048) {
            const int bb = (int)(bm >> 11);
            const int n0 = (int)(bm & 2047) + wm + l4 * 4;
#pragma unroll
            for (int nf = 0; nf < NFR; ++nf) {
                const int d = (int)(bn - 2048) + wn + nf * 16 + l15;
                unsigned short* vrow = vt_out + ((size_t)(bb * 16 + (d >> 6)) * 64 + (d & 63)) * 2048;
#pragma unroll
                for (int mf = 0; mf < MFR; ++mf) {
                    union { unsigned short s[4]; uint64_t q; } u;
#pragma unroll
                    for (int j = 0; j < 4; ++j) u.s[j] = f2bf(acc[mf][nf][j]);
                    *(uint64_t*)(vrow + n0 + mf * 16) = u.q;
                }
            }
        } else {
            unsigned short* C = (unsigned short*)Cp;
#pragma unroll
            for (int mf = 0; mf < MFR; ++mf)
#pragma unroll
                for (int nf = 0; nf < NFR; ++nf) {
                    const size_t row = bm + wm + mf * 16 + l4 * 4;
                    const size_t col = bn + wn + nf * 16 + l15;
#pragma unroll
                    for (int j = 0; j < 4; ++j)
                        C[(row + j) * (size_t)N + col] = f2bf(acc[mf][nf][j]);
                }
        }
    } else {
        float* C = (float*)Cp;
#pragma unroll
        for (int nf = 0; nf < NFR; ++nf) {
            const size_t col = bn + wn + nf * 16 + l15;
            const float bv = bias[col];
#pragma unroll
            for (int mf = 0; mf < MFR; ++mf) {
                const size_t row = bm + wm + mf * 16 + l4 * 4;
#pragma unroll
                for (int j = 0; j < 4; ++j)
                    C[(row + j) * (size_t)N + col] = acc[mf][nf][j] + bv;
            }
        }
    }
}

// ---------------------------------------------------------------------------
// 5) Flash attention — R9/R11-exact inner loop. New: 1D grid (1024 blocks)
//    with XCD-aware swizzle, bh-major work order: XCD r owns bh in
//    [4r, 4r+4) whose K/V working set (2 MB) is L2-resident -> the 32
//    q-tile blocks sharing a bh hit L2 instead of streaming HBM.
// ---------------------------------------------------------------------------
__global__ __launch_bounds__(256, 4)
void k_attn(const unsigned short* __restrict__ qkv, const unsigned short* __restrict__ vt,
            unsigned short* __restrict__ attn_out) {
    __shared__ alignas(16) unsigned short lK[2][64 * 64];
    __shared__ alignas(16) unsigned short lV[2][64 * 64];
    __shared__ alignas(16) unsigned short lP[4][16 * 64];
    const int t = threadIdx.x, w = t >> 6, l = t & 63;
    const int l15 = l & 15, l4 = l >> 4;
    // XCD swizzle: 1024 blocks, cpx = 128; work = bh*32 + qtile (bh-major)
    const int wk = (blockIdx.x & 7) * 128 + (blockIdx.x >> 3);
    const int bh = wk >> 5, b = bh >> 4, h = bh & 15;
    const int qb = (wk & 31) * 64;
    const float QSCALE = 0.18033688011112042f;   // 0.125 * log2(e)

    const unsigned short* qptr =
        qkv + (size_t)(b * 2048 + qb + w * 16 + l15) * 3072 + h * 64 + l4 * 8;
    const bf16x8 aq0 = *(const bf16x8*)(qptr);
    const bf16x8 aq1 = *(const bf16x8*)(qptr + 32);

    const int srow = t >> 3, sslot = t & 7;
    const int swoff = srow * 64 + ((sslot ^ (srow & 7)) << 3);
    const unsigned short* kptr = qkv + (size_t)(b * 2048 + srow) * 3072 + 1024 + h * 64 + sslot * 8;
    const unsigned short* vptr = vt + (size_t)(bh * 64 + srow) * 2048 + sslot * 8;

    int offK[4][2];
#pragma unroll
    for (int nf = 0; nf < 4; ++nf) {
        const int r = nf * 16 + l15;
#pragma unroll
        for (int kc = 0; kc < 2; ++kc)
            offK[nf][kc] = r * 64 + (((kc * 4 + l4) ^ (r & 7)) << 3);
    }
    int offPw[4];
#pragma unroll
    for (int nf = 0; nf < 4; ++nf) {
        const int c = nf * 16 + l4 * 4;
        offPw[nf] = l15 * 64 + (((c >> 3) ^ (l15 & 7)) << 3) + (c & 7);
    }

    const f32x4 zf = {0.f, 0.f, 0.f, 0.f};
    f32x4 o[4];
#pragma unroll
    for (int df = 0; df < 4; ++df) o[df] = zf;
    f32x4 accl = zf;
    float m_run = -1e30f;
    unsigned short* Pw = &lP[w][0];
    const bf16x8 ones8 = {(short)0x3F80, (short)0x3F80, (short)0x3F80, (short)0x3F80,
                          (short)0x3F80, (short)0x3F80, (short)0x3F80, (short)0x3F80};

    // prologue: stage tile 0 into buffer 0
    {
        bf16x8 rk[2], rv[2];
#pragma unroll
        for (int p = 0; p < 2; ++p) {
            rk[p] = *(const bf16x8*)(kptr + (size_t)(p * 32) * 3072);
            rv[p] = *(const bf16x8*)(vptr + (size_t)(p * 32) * 2048);
        }
#pragma unroll
        for (int p = 0; p < 2; ++p) {
            *(bf16x8*)(&lK[0][0] + p * 32 * 64 + swoff) = rk[p];
            *(bf16x8*)(&lV[0][0] + p * 32 * 64 + swoff) = rv[p];
        }
        __syncthreads();
    }

#pragma unroll 2
    for (int kt = 0; kt < 2048; kt += 64) {
        const int cur = (kt >> 6) & 1;
        const unsigned short* K = &lK[cur][0];
        const unsigned short* V = &lV[cur][0];

        bf16x8 rk[2], rv[2];
        const bool more = (kt + 64) < 2048;
        if (more) {
#pragma unroll
            for (int p = 0; p < 2; ++p) {
                rk[p] = *(const bf16x8*)(kptr + (size_t)(kt + 64 + p * 32) * 3072);
                rv[p] = *(const bf16x8*)(vptr + (size_t)(p * 32) * 2048 + kt + 64);
            }
        }

        // S^T = K Q^T : lane holds S_raw[kv = nf*16 + l4*4 + j][q = l15]
        f32x4 s[4];
        __builtin_amdgcn_s_setprio(1);
#pragma unroll
        for (int nf = 0; nf < 4; ++nf) {
            const bf16x8 kf0 = *(const bf16x8*)(K + offK[nf][0]);
            const bf16x8 kf1 = *(const bf16x8*)(K + offK[nf][1]);
            f32x4 a = zf;
            a = __builtin_amdgcn_mfma_f32_16x16x32_bf16(kf0, aq0, a, 0, 0, 0);
            a = __builtin_amdgcn_mfma_f32_16x16x32_bf16(kf1, aq1, a, 0, 0, 0);
            s[nf] = a;
        }
        __builtin_amdgcn_s_setprio(0);

        // row max over 16 lane-local values + 2 shfl across the 4 dup lanes
        float mx = fmaxf(fmaxf(s[0][0], s[0][1]), s[0][2]);
        mx = fmaxf(fmaxf(mx, s[0][3]), s[1][0]);
        mx = fmaxf(fmaxf(mx, s[1][1]), s[1][2]);
        mx = fmaxf(fmaxf(mx, s[1][3]), s[2][0]);
        mx = fmaxf(fmaxf(mx, s[2][1]), s[2][2]);
        mx = fmaxf(fmaxf(mx, s[2][3]), s[3][0]);
        mx = fmaxf(fmaxf(mx, s[3][1]), s[3][2]);
        mx = fmaxf(mx, s[3][3]);
        mx = fmaxf(mx, __shfl_xor(mx, 16));
        mx = fmaxf(mx, __shfl_xor(mx, 32));
        mx *= QSCALE;

        // defer-max: rescale only when the row max grew by > 8 (log2 domain)
        if (!__all(mx <= m_run + 8.0f)) {
            const float mn = fmaxf(m_run, mx);
            const float alpha = exp2f(m_run - mn);
            m_run = mn;
            const float a0 = __shfl(alpha, l4 * 4 + 0);
            const float a1 = __shfl(alpha, l4 * 4 + 1);
            const float a2 = __shfl(alpha, l4 * 4 + 2);
            const float a3 = __shfl(alpha, l4 * 4 + 3);
#pragma unroll
            for (int df = 0; df < 4; ++df) {
                o[df][0] *= a0; o[df][1] *= a1; o[df][2] *= a2; o[df][3] *= a3;
            }
            accl[0] *= a0; accl[1] *= a1; accl[2] *= a2; accl[3] *= a3;
        }

        // P = exp2(QSCALE*s_raw - m), packed to per-wave LDS (b64 writes)
#pragma unroll
        for (int nf = 0; nf < 4; ++nf) {
            const float p0 = exp2f(fmaf(s[nf][0], QSCALE, -m_run));
            const float p1 = exp2f(fmaf(s[nf][1], QSCALE, -m_run));
            const float p2 = exp2f(fmaf(s[nf][2], QSCALE, -m_run));
            const float p3 = exp2f(fmaf(s[nf][3], QSCALE, -m_run));
            union { unsigned int d[2]; uint64_t q; } u;
            u.d[0] = cvt_pk_bf16(p0, p1);
            u.d[1] = cvt_pk_bf16(p2, p3);
            *(uint64_t*)(Pw + offPw[nf]) = u.q;
        }

        // O += P V ; rowsum via ones-column on the MFMA pipe
        const bf16x8 ap0 = *(const bf16x8*)(Pw + l15 * 64 + ((l4 ^ (l15 & 7)) << 3));
        const bf16x8 ap1 = *(const bf16x8*)(Pw + l15 * 64 + (((4 + l4) ^ (l15 & 7)) << 3));
        __builtin_amdgcn_s_setprio(1);
        accl = __builtin_amdgcn_mfma_f32_16x16x32_bf16(ap0, ones8, accl, 0, 0, 0);
        accl = __builtin_amdgcn_mfma_f32_16x16x32_bf16(ap1, ones8, accl, 0, 0, 0);
#pragma unroll
        for (int df = 0; df < 4; ++df) {
            const int r = df * 16 + l15;
            const bf16x8 bv0 = *(const bf16x8*)(V + r * 64 + ((l4 ^ (r & 7)) << 3));
            const bf16x8 bv1 = *(const bf16x8*)(V + r * 64 + (((4 + l4) ^ (r & 7)) << 3));
            o[df] = __builtin_amdgcn_mfma_f32_16x16x32_bf16(ap0, bv0, o[df], 0, 0, 0);
            o[df] = __builtin_amdgcn_mfma_f32_16x16x32_bf16(ap1, bv1, o[df], 0, 0, 0);
        }
        __builtin_amdgcn_s_setprio(0);

        if (more) {
#pragma unroll
            for (int p = 0; p < 2; ++p) {
                *(bf16x8*)(&lK[cur ^ 1][0] + p * 32 * 64 + swoff) = rk[p];
                *(bf16x8*)(&lV[cur ^ 1][0] + p * 32 * 64 + swoff) = rv[p];
            }
        }
        __syncthreads();
    }

    // epilogue: O / l  (accl rows aligned with o rows -> no shuffles)
    const float r0 = 1.0f / accl[0];
    const float r1 = 1.0f / accl[1];
    const float r2 = 1.0f / accl[2];
    const float r3 = 1.0f / accl[3];
    const int rowb = b * 2048 + qb + w * 16 + l4 * 4;
#pragma unroll
    for (int df = 0; df < 4; ++df) {
        const int d = df * 16 + l15;
        attn_out[(size_t)(rowb + 0) * 1024 + h * 64 + d] = f2bf(o[df][0] * r0);
        attn_out[(size_t)(rowb + 1) * 1024 + h * 64 + d] = f2bf(o[df][1] * r1);
        attn_out[(size_t)(rowb + 2) * 1024 + h * 64 + d] = f2bf(o[df][2] * r2);
        attn_out[(size_t)(rowb + 3) * 1024 + h * 64 + d] = f2bf(o[df][3] * r3);
    }
}

// ---------------------------------------------------------------------------
extern "C" void kernel_launch(void* const* d_in, const int* in_sizes, int n_in,
                              void* d_out, int out_size, void* d_ws, size_t ws_size,
                              hipStream_t stream) {
    const float* x      = (const float*)d_in[0];
    const float* w_qkv  = (const float*)d_in[1];
    const float* w_proj = (const float*)d_in[2];
    const float* b_proj = (const float*)d_in[3];
    float* out = (float*)d_out;

    char* ws = (char*)d_ws;
    unsigned short* xb     = (unsigned short*)(ws + 0);           //  8M
    unsigned short* wqkvT  = (unsigned short*)(ws + 8388608);     //  6M
    unsigned short* wprojT = (unsigned short*)(ws + 14680064);    //  2M
    unsigned short* qkv    = (unsigned short*)(ws + 16777216);    // 24M
    unsigned short* vt     = (unsigned short*)(ws + 41943040);    //  8M
    unsigned short* attn   = (unsigned short*)(ws + 50331648);    //  8M

    k_cvt_all<<<dim3(5120), dim3(256), 0, stream>>>(x, xb, w_qkv, wqkvT, w_proj, wprojT);
    // QKV GEMM: 768 blocks (24 n-tiles x 32 m-tiles), XCD-grouped B panels
    k_gemm_bt<1, 128, 128, 32><<<dim3(768), dim3(256), 0, stream>>>(
        xb, wqkvT, (void*)qkv, (const float*)nullptr, vt, 4096, 3072, 1024);
    // attention: 1024 blocks, bh-grouped per XCD
    k_attn<<<dim3(1024), dim3(256), 0, stream>>>(qkv, vt, attn);
    // proj GEMM: 1024 blocks (16 n-tiles x 64 m-tiles)
    k_gemm_bt<0, 64, 64, 64><<<dim3(1024), dim3(256), 0, stream>>>(
        attn, wprojT, (void*)out, b_proj, (unsigned short*)nullptr, 4096, 1024, 1024);
}